// Round 1
// baseline (457.009 us; speedup 1.0000x reference)
//
#include <hip/hip_runtime.h>
#include <hip/hip_bf16.h>

#define BATCH 16384
#define HID   1024
#define EMBD  512
#define NOPS  8
#define MAXT  136   // max tile slots: sum ceil(cnt_e/128) <= 135

typedef __attribute__((ext_vector_type(8))) short bf16x8;
typedef __attribute__((ext_vector_type(4))) float f32x4;

__device__ __forceinline__ unsigned short f2bf(float f) {
  unsigned int u = __float_as_uint(f);
  u += 0x7FFF + ((u >> 16) & 1);
  return (unsigned short)(u >> 16);
}

__device__ __forceinline__ unsigned int pk2(float a, float b) {
  __hip_bfloat162 t = __float22bfloat162_rn(make_float2(a, b));
  return *(unsigned int*)(&t);
}

__device__ __forceinline__ void lds_load16(void* lds, const void* g) {
  __builtin_amdgcn_global_load_lds(
      (const __attribute__((address_space(1))) unsigned int*)g,
      (__attribute__((address_space(3))) unsigned int*)lds, 16, 0, 0);
}

// ---------------- phase 0: bucket tokens by expert ----------------
__global__ void bucket_k(const int* __restrict__ ops, int* __restrict__ cnt,
                         int* __restrict__ idx) {
  int t = blockIdx.x * 256 + threadIdx.x;
  int op = ops[t];
  int slot = atomicAdd(&cnt[op], 1);
  idx[op * BATCH + slot] = t;
}

// build tile descriptors + pad index lists to tile multiples
__global__ void schedule_k(const int* __restrict__ cnt, int* __restrict__ desc,
                           int* __restrict__ ntp, int* __restrict__ idx) {
  if (threadIdx.x == 0) {
    int n = 0;
    for (int e = 0; e < NOPS; ++e) {
      int c = cnt[e];
      for (int t = 0; t < c; t += 128) { desc[2 * n] = e; desc[2 * n + 1] = t; ++n; }
    }
    *ntp = n;
  }
  for (int e = 0; e < NOPS; ++e) {
    int c = cnt[e];
    int cp = (c + 127) & ~127;
    for (int p = c + (int)threadIdx.x; p < cp; p += 256) idx[e * BATCH + p] = 0;
  }
}

// ---------------- phase 1: convert + transpose + pre-tile weights ----------------
// W1p slab (e, nx, ks): [128 n][32 k] bf16 where value = W1[e][ks*32+k][nx*128+n]
__global__ void prep_w_k(const float* __restrict__ W1, const float* __restrict__ W2,
                         short* __restrict__ W1p, short* __restrict__ W2p) {
  int bid = blockIdx.x;
  const float* W; short* Wp; int ks, nx;
  if (bid < 3072) {               // W1: 8 e * 8 nx * 48 ks
    int e = bid / 384; int r = bid % 384; nx = r / 48; ks = r % 48;
    W = W1 + (size_t)e * 1536 * 1024;
    Wp = W1p + ((size_t)(e * 8 + nx) * 48 + ks) * 4096;
  } else {                        // W2: 8 e * 8 nx * 32 ks
    int b = bid - 3072;
    int e = b / 256; int r = b % 256; nx = r / 32; ks = r % 32;
    W = W2 + (size_t)e * 1024 * 1024;
    Wp = W2p + ((size_t)(e * 8 + nx) * 32 + ks) * 4096;
  }
  __shared__ __align__(16) unsigned short ls[4096];
  int tid = threadIdx.x;
  int nl = (tid & 31) * 4, kl = tid >> 5;     // n base 0..124, k base 0..7
#pragma unroll
  for (int c = 0; c < 4; ++c) {
    int k = kl + c * 8;
    float4 f = *(const float4*)(W + (size_t)(ks * 32 + k) * 1024 + nx * 128 + nl);
    ls[(nl + 0) * 32 + k] = f2bf(f.x);
    ls[(nl + 1) * 32 + k] = f2bf(f.y);
    ls[(nl + 2) * 32 + k] = f2bf(f.z);
    ls[(nl + 3) * 32 + k] = f2bf(f.w);
  }
  __syncthreads();
  uint4* d4 = (uint4*)Wp;
  const uint4* s4 = (const uint4*)ls;
  d4[tid * 2] = s4[tid * 2];
  d4[tid * 2 + 1] = s4[tid * 2 + 1];
}

// ---------------- phase 2: GEMM1  h = relu([x,emb] @ W1[e] + b1[e]) ----------------
__global__ __launch_bounds__(256) void gemm1_k(
    const float* __restrict__ x, const float* __restrict__ emb,
    const float* __restrict__ b1, const short* __restrict__ W1p,
    unsigned short* __restrict__ hp, const int* __restrict__ idx,
    const int* __restrict__ desc, const int* __restrict__ ntp) {
  int g = blockIdx.y;
  if (g >= *ntp) return;
  int nx = blockIdx.x;
  int e = desc[2 * g], rs = desc[2 * g + 1];

  __shared__ __align__(16) short lA[128 * 32];
  __shared__ __align__(16) short lB[128 * 32];
  __shared__ int toks[128];

  int tid = threadIdx.x;
  if (tid < 128) toks[tid] = idx[e * BATCH + rs + tid];
  __syncthreads();

  int lane = tid & 63, w = tid >> 6;
  int wm = w >> 1, wn = w & 1;
  int fr = lane & 15, fq = lane >> 4;

  int ar = tid >> 1, ah = tid & 1;            // A staging: 2 threads per row
  int tok = toks[ar];
  const float* xrow = x + (size_t)tok * HID + ah * 16;
  const float* erow = emb + e * EMBD + ah * 16;
  short* aw = &lA[ar * 32 + ah * 16];

  const char* Bsrc = (const char*)W1p + (size_t)(e * 8 + nx) * 48 * 8192;
  char* lBc = (char*)lB;

  f32x4 acc[4][4] = {};

  for (int ks = 0; ks < 48; ++ks) {
    const char* bs = Bsrc + ks * 8192;
    lds_load16(lBc + w * 1024, bs + w * 1024 + lane * 16);
    lds_load16(lBc + 4096 + w * 1024, bs + 4096 + w * 1024 + lane * 16);

    const float* src = (ks < 32) ? (xrow + ks * 32) : (erow + (ks - 32) * 32);
    float4 f0 = ((const float4*)src)[0];
    float4 f1 = ((const float4*)src)[1];
    float4 f2v = ((const float4*)src)[2];
    float4 f3 = ((const float4*)src)[3];
    uint4 p0 = make_uint4(pk2(f0.x, f0.y), pk2(f0.z, f0.w), pk2(f1.x, f1.y), pk2(f1.z, f1.w));
    uint4 p1 = make_uint4(pk2(f2v.x, f2v.y), pk2(f2v.z, f2v.w), pk2(f3.x, f3.y), pk2(f3.z, f3.w));
    ((uint4*)aw)[0] = p0;
    ((uint4*)aw)[1] = p1;
    __syncthreads();

    bf16x8 af[4], bfr[4];
#pragma unroll
    for (int i = 0; i < 4; ++i)
      af[i] = *(const bf16x8*)&lA[(wm * 64 + i * 16 + fr) * 32 + fq * 8];
#pragma unroll
    for (int j = 0; j < 4; ++j)
      bfr[j] = *(const bf16x8*)&lB[(wn * 64 + j * 16 + fr) * 32 + fq * 8];
#pragma unroll
    for (int i = 0; i < 4; ++i)
#pragma unroll
      for (int j = 0; j < 4; ++j)
        acc[i][j] = __builtin_amdgcn_mfma_f32_16x16x32_bf16(af[i], bfr[j], acc[i][j], 0, 0, 0);
    __syncthreads();
  }

  int col0 = nx * 128 + wn * 64;
  int row0 = wm * 64;
#pragma unroll
  for (int j = 0; j < 4; ++j) {
    int ng = col0 + j * 16 + fr;
    float bias = b1[e * HID + ng];
    unsigned short* hb = hp + ((size_t)(g * 32 + (ng >> 5)) * 128) * 32 + (ng & 31);
#pragma unroll
    for (int i = 0; i < 4; ++i) {
      int r0 = row0 + i * 16 + fq * 4;
#pragma unroll
      for (int rg = 0; rg < 4; ++rg) {
        float v = acc[i][j][rg] + bias;
        v = v > 0.f ? v : 0.f;
        hb[(size_t)(r0 + rg) * 32] = f2bf(v);
      }
    }
  }
}

// ---------------- phase 3: GEMM2  out[tok] = relu(h @ W2[e] + b2[e]) ----------------
__global__ __launch_bounds__(256) void gemm2_k(
    const unsigned short* __restrict__ hp, const float* __restrict__ b2,
    const short* __restrict__ W2p, float* __restrict__ out,
    const int* __restrict__ idx, const int* __restrict__ cnt,
    const int* __restrict__ desc, const int* __restrict__ ntp) {
  int g = blockIdx.y;
  if (g >= *ntp) return;
  int nx = blockIdx.x;
  int e = desc[2 * g], rs = desc[2 * g + 1];
  int ce = cnt[e];

  __shared__ __align__(16) short lA[128 * 32];
  __shared__ __align__(16) short lB[128 * 32];
  __shared__ int toks[128];

  int tid = threadIdx.x;
  if (tid < 128) toks[tid] = idx[e * BATCH + rs + tid];

  int lane = tid & 63, w = tid >> 6;
  int wm = w >> 1, wn = w & 1;
  int fr = lane & 15, fq = lane >> 4;

  const char* Asrc = (const char*)hp + (size_t)g * 32 * 8192;
  const char* Bsrc = (const char*)W2p + (size_t)(e * 8 + nx) * 32 * 8192;
  char* lAc = (char*)lA;
  char* lBc = (char*)lB;

  f32x4 acc[4][4] = {};

  for (int ks = 0; ks < 32; ++ks) {
    const char* as = Asrc + ks * 8192;
    const char* bs = Bsrc + ks * 8192;
    lds_load16(lAc + w * 1024, as + w * 1024 + lane * 16);
    lds_load16(lAc + 4096 + w * 1024, as + 4096 + w * 1024 + lane * 16);
    lds_load16(lBc + w * 1024, bs + w * 1024 + lane * 16);
    lds_load16(lBc + 4096 + w * 1024, bs + 4096 + w * 1024 + lane * 16);
    __syncthreads();

    bf16x8 af[4], bfr[4];
#pragma unroll
    for (int i = 0; i < 4; ++i)
      af[i] = *(const bf16x8*)&lA[(wm * 64 + i * 16 + fr) * 32 + fq * 8];
#pragma unroll
    for (int j = 0; j < 4; ++j)
      bfr[j] = *(const bf16x8*)&lB[(wn * 64 + j * 16 + fr) * 32 + fq * 8];
#pragma unroll
    for (int i = 0; i < 4; ++i)
#pragma unroll
      for (int j = 0; j < 4; ++j)
        acc[i][j] = __builtin_amdgcn_mfma_f32_16x16x32_bf16(af[i], bfr[j], acc[i][j], 0, 0, 0);
    __syncthreads();
  }

  int col0 = nx * 128 + wn * 64;
  int row0 = wm * 64;
#pragma unroll
  for (int j = 0; j < 4; ++j) {
    int ng = col0 + j * 16 + fr;
    float bias = b2[e * HID + ng];
#pragma unroll
    for (int i = 0; i < 4; ++i) {
      int r0 = row0 + i * 16 + fq * 4;
#pragma unroll
      for (int rg = 0; rg < 4; ++rg) {
        int r = r0 + rg;
        if (r < ce - rs) {
          float v = acc[i][j][rg] + bias;
          out[(size_t)toks[r] * HID + ng] = v > 0.f ? v : 0.f;
        }
      }
    }
  }
}

// ---------------- workspace layout (bytes) ----------------
// cnt     @ 0        (32)
// ntiles  @ 128      (4)
// desc    @ 256      (136*2*4 = 1088)
// idx     @ 4096     (8*16384*4 = 524288)
// W1p     @ 528384   (8*1536*1024*2 = 25165824)
// W2p     @ 25694208 (8*1024*1024*2 = 16777216)
// hp      @ 42471424 (136*1024*128*2 = 35651584)  -> end 78123008 (~78.1 MB)

extern "C" void kernel_launch(void* const* d_in, const int* in_sizes, int n_in,
                              void* d_out, int out_size, void* d_ws, size_t ws_size,
                              hipStream_t stream) {
  const float* x   = (const float*)d_in[0];
  const int*   ops = (const int*)d_in[1];
  const float* emb = (const float*)d_in[2];
  const float* W1  = (const float*)d_in[3];
  const float* b1  = (const float*)d_in[4];
  const float* W2  = (const float*)d_in[5];
  const float* b2  = (const float*)d_in[6];
  float* out = (float*)d_out;

  char* ws = (char*)d_ws;
  int* cnt  = (int*)(ws + 0);
  int* ntp  = (int*)(ws + 128);
  int* desc = (int*)(ws + 256);
  int* idx  = (int*)(ws + 4096);
  short* W1p = (short*)(ws + 528384);
  short* W2p = (short*)(ws + 25694208);
  unsigned short* hp = (unsigned short*)(ws + 42471424);

  hipMemsetAsync(cnt, 0, 32, stream);
  bucket_k<<<BATCH / 256, 256, 0, stream>>>(ops, cnt, idx);
  schedule_k<<<1, 256, 0, stream>>>(cnt, desc, ntp, idx);
  prep_w_k<<<3072 + 2048, 256, 0, stream>>>(W1, W2, W1p, W2p);

  dim3 grid(8, MAXT);
  gemm1_k<<<grid, 256, 0, stream>>>(x, emb, b1, W1p, hp, idx, desc, ntp);
  gemm2_k<<<grid, 256, 0, stream>>>(hp, b2, W2p, out, idx, cnt, desc, ntp);
}

// Round 2
// 380.878 us; speedup vs baseline: 1.1999x; 1.1999x over previous
//
#include <hip/hip_runtime.h>
#include <hip/hip_bf16.h>

#define BATCH 16384
#define HID   1024
#define EMBD  512
#define NOPS  8
#define MAXT  136   // max tile slots: sum ceil(cnt_e/128) <= 135

typedef __attribute__((ext_vector_type(8))) short bf16x8;
typedef __attribute__((ext_vector_type(4))) float f32x4;

__device__ __forceinline__ unsigned short f2bf(float f) {
  unsigned int u = __float_as_uint(f);
  u += 0x7FFF + ((u >> 16) & 1);
  return (unsigned short)(u >> 16);
}

__device__ __forceinline__ unsigned int pk2(float a, float b) {
  __hip_bfloat162 t = __float22bfloat162_rn(make_float2(a, b));
  return *(unsigned int*)(&t);
}

__device__ __forceinline__ void lds_load16(void* lds, const void* g) {
  __builtin_amdgcn_global_load_lds(
      (const __attribute__((address_space(1))) unsigned int*)g,
      (__attribute__((address_space(3))) unsigned int*)lds, 16, 0, 0);
}

// ---------------- phase 0: bucket tokens by expert (wave-aggregated atomics) ----
__global__ void bucket_k(const int* __restrict__ ops, int* __restrict__ cnt,
                         int* __restrict__ idx) {
  int t = blockIdx.x * 256 + threadIdx.x;
  int op = ops[t];
  int lane = threadIdx.x & 63;
#pragma unroll
  for (int o = 0; o < NOPS; ++o) {
    unsigned long long m = __ballot(op == o);
    if (op == o) {
      int leader = __ffsll((unsigned long long)m) - 1;
      int pre = __popcll(m & ((1ull << lane) - 1ull));
      int base = 0;
      if (lane == leader) base = atomicAdd(&cnt[o], __popcll(m));
      base = __shfl(base, leader);
      idx[o * BATCH + base + pre] = t;
    }
  }
}

// build tile descriptors + pad index lists to tile multiples
__global__ void schedule_k(const int* __restrict__ cnt, int* __restrict__ desc,
                           int* __restrict__ ntp, int* __restrict__ idx) {
  if (threadIdx.x == 0) {
    int n = 0;
    for (int e = 0; e < NOPS; ++e) {
      int c = cnt[e];
      for (int t = 0; t < c; t += 128) { desc[2 * n] = e; desc[2 * n + 1] = t; ++n; }
    }
    *ntp = n;
  }
  for (int e = 0; e < NOPS; ++e) {
    int c = cnt[e];
    int cp = (c + 127) & ~127;
    for (int p = c + (int)threadIdx.x; p < cp; p += 256) idx[e * BATCH + p] = 0;
  }
}

// ---------------- phase 1a: convert + transpose + pre-tile weights ----------------
// W1p slab (e, nx, ks): [128 n][32 k] bf16 where value = W1[e][ks*32+k][nx*128+n]
__global__ void prep_w_k(const float* __restrict__ W1, const float* __restrict__ W2,
                         short* __restrict__ W1p, short* __restrict__ W2p) {
  int bid = blockIdx.x;
  const float* W; short* Wp; int ks, nx;
  if (bid < 3072) {               // W1: 8 e * 8 nx * 48 ks
    int e = bid / 384; int r = bid % 384; nx = r / 48; ks = r % 48;
    W = W1 + (size_t)e * 1536 * 1024;
    Wp = W1p + ((size_t)(e * 8 + nx) * 48 + ks) * 4096;
  } else {                        // W2: 8 e * 8 nx * 32 ks
    int b = bid - 3072;
    int e = b / 256; int r = b % 256; nx = r / 32; ks = r % 32;
    W = W2 + (size_t)e * 1024 * 1024;
    Wp = W2p + ((size_t)(e * 8 + nx) * 32 + ks) * 4096;
  }
  __shared__ __align__(16) unsigned short ls[4096];
  int tid = threadIdx.x;
  int nl = (tid & 31) * 4, kl = tid >> 5;     // n base 0..124, k base 0..7
#pragma unroll
  for (int c = 0; c < 4; ++c) {
    int k = kl + c * 8;
    float4 f = *(const float4*)(W + (size_t)(ks * 32 + k) * 1024 + nx * 128 + nl);
    ls[(nl + 0) * 32 + k] = f2bf(f.x);
    ls[(nl + 1) * 32 + k] = f2bf(f.y);
    ls[(nl + 2) * 32 + k] = f2bf(f.z);
    ls[(nl + 3) * 32 + k] = f2bf(f.w);
  }
  __syncthreads();
  uint4* d4 = (uint4*)Wp;
  const uint4* s4 = (const uint4*)ls;
  d4[tid * 2] = s4[tid * 2];
  d4[tid * 2 + 1] = s4[tid * 2 + 1];
}

// ---------------- phase 1b: gather + convert + pre-tile A = [x | emb] ----------
// Ap slab (g, ks): [128 r][32 k] bf16, rows are the tile's gathered tokens.
__global__ void prep_a_k(const float* __restrict__ x, const float* __restrict__ emb,
                         const int* __restrict__ idx, const int* __restrict__ desc,
                         const int* __restrict__ ntp, short* __restrict__ Ap) {
  int g = blockIdx.y;
  if (g >= *ntp) return;
  int e = desc[2 * g], rs = desc[2 * g + 1];
  __shared__ int toks[128];
  int tid = threadIdx.x;
  if (tid < 128) toks[tid] = idx[e * BATCH + rs + tid];
  __syncthreads();
  int r = tid >> 1, ah = tid & 1;
  int tok = toks[r];
  short* dst0 = Ap + (size_t)g * 48 * 4096;
#pragma unroll
  for (int kk = 0; kk < 4; ++kk) {
    int ks = blockIdx.x * 4 + kk;
    const float* src = (ks < 32) ? (x + (size_t)tok * HID + ks * 32 + ah * 16)
                                 : (emb + e * EMBD + (ks - 32) * 32 + ah * 16);
    float4 f0 = ((const float4*)src)[0];
    float4 f1 = ((const float4*)src)[1];
    float4 f2v = ((const float4*)src)[2];
    float4 f3 = ((const float4*)src)[3];
    uint4 p0 = make_uint4(pk2(f0.x, f0.y), pk2(f0.z, f0.w), pk2(f1.x, f1.y), pk2(f1.z, f1.w));
    uint4 p1 = make_uint4(pk2(f2v.x, f2v.y), pk2(f2v.z, f2v.w), pk2(f3.x, f3.y), pk2(f3.z, f3.w));
    short* dst = dst0 + ks * 4096 + r * 32 + ah * 16;
    ((uint4*)dst)[0] = p0;
    ((uint4*)dst)[1] = p1;
  }
}

// ---------------- phase 2: GEMM1  h = relu(A @ W1[e] + b1[e]) ----------------
__global__ __launch_bounds__(256) void gemm1_k(
    const short* __restrict__ Ap, const float* __restrict__ b1,
    const short* __restrict__ W1p, unsigned short* __restrict__ hp,
    const int* __restrict__ desc, const int* __restrict__ ntp) {
  int g = blockIdx.y;
  if (g >= *ntp) return;
  int nx = blockIdx.x;
  int e = desc[2 * g];

  __shared__ __align__(16) char smem[16384];
  short* lA = (short*)smem;
  short* lB = (short*)(smem + 8192);

  int tid = threadIdx.x, lane = tid & 63, w = tid >> 6;
  int wm = w >> 1, wn = w & 1;
  int fr = lane & 15, fq = lane >> 4;

  const char* Asrc = (const char*)Ap + (size_t)g * 48 * 8192;
  const char* Bsrc = (const char*)W1p + (size_t)(e * 8 + nx) * 48 * 8192;

  f32x4 acc[4][4] = {};

  for (int ks = 0; ks < 48; ++ks) {
    const char* as = Asrc + ks * 8192;
    const char* bs = Bsrc + ks * 8192;
    lds_load16(smem + w * 1024, as + w * 1024 + lane * 16);
    lds_load16(smem + 4096 + w * 1024, as + 4096 + w * 1024 + lane * 16);
    lds_load16(smem + 8192 + w * 1024, bs + w * 1024 + lane * 16);
    lds_load16(smem + 12288 + w * 1024, bs + 4096 + w * 1024 + lane * 16);
    __syncthreads();

    bf16x8 af[4], bfr[4];
#pragma unroll
    for (int i = 0; i < 4; ++i)
      af[i] = *(const bf16x8*)&lA[(wm * 64 + i * 16 + fr) * 32 + fq * 8];
#pragma unroll
    for (int j = 0; j < 4; ++j)
      bfr[j] = *(const bf16x8*)&lB[(wn * 64 + j * 16 + fr) * 32 + fq * 8];
#pragma unroll
    for (int i = 0; i < 4; ++i)
#pragma unroll
      for (int j = 0; j < 4; ++j)
        acc[i][j] = __builtin_amdgcn_mfma_f32_16x16x32_bf16(af[i], bfr[j], acc[i][j], 0, 0, 0);
    __syncthreads();
  }

  // epilogue: bias + relu + bf16, coalesced via LDS round-trip.
  // hp layout: [g][ks2(32)][128 r][32 k] so gemm2 A-staging is contiguous.
  float bias[4];
#pragma unroll
  for (int j = 0; j < 4; ++j)
    bias[j] = b1[e * HID + nx * 128 + wn * 64 + j * 16 + fr];

  unsigned short* ls = (unsigned short*)smem;   // per-wave 1024 ushorts @ w*1024
  int lr = lane >> 2;
#pragma unroll
  for (int i = 0; i < 4; ++i) {
    __syncthreads();
#pragma unroll
    for (int j = 0; j < 4; ++j)
#pragma unroll
      for (int rg = 0; rg < 4; ++rg) {
        float v = acc[i][j][rg] + bias[j];
        v = v > 0.f ? v : 0.f;
        ls[w * 1024 + (fq * 4 + rg) * 64 + j * 16 + fr] = f2bf(v);
      }
    __syncthreads();
    int R = wm * 64 + i * 16 + lr;
#pragma unroll
    for (int s = 0; s < 2; ++s) {
      int ch = (lane & 3) + s * 4;
      int ks2 = nx * 4 + wn * 2 + (ch >> 2);
      uint4 val = *(const uint4*)&ls[w * 1024 + lr * 64 + ch * 8];
      *(uint4*)(hp + ((size_t)(g * 32 + ks2) * 128 + R) * 32 + (ch & 3) * 8) = val;
    }
  }
}

// ---------------- phase 3: GEMM2  out[tok] = relu(h @ W2[e] + b2[e]) ----------------
__global__ __launch_bounds__(256) void gemm2_k(
    const unsigned short* __restrict__ hp, const float* __restrict__ b2,
    const short* __restrict__ W2p, float* __restrict__ out,
    const int* __restrict__ idx, const int* __restrict__ cnt,
    const int* __restrict__ desc, const int* __restrict__ ntp) {
  int g = blockIdx.y;
  if (g >= *ntp) return;
  int nx = blockIdx.x;
  int e = desc[2 * g], rs = desc[2 * g + 1];
  int ce = cnt[e];

  __shared__ __align__(16) char smem[16384];
  __shared__ int toks[128];
  short* lA = (short*)smem;
  short* lB = (short*)(smem + 8192);

  int tid = threadIdx.x, lane = tid & 63, w = tid >> 6;
  int wm = w >> 1, wn = w & 1;
  int fr = lane & 15, fq = lane >> 4;

  if (tid < 128) toks[tid] = idx[e * BATCH + rs + tid];

  const char* Asrc = (const char*)hp + (size_t)g * 32 * 8192;
  const char* Bsrc = (const char*)W2p + (size_t)(e * 8 + nx) * 32 * 8192;

  f32x4 acc[4][4] = {};

  for (int ks = 0; ks < 32; ++ks) {
    const char* as = Asrc + ks * 8192;
    const char* bs = Bsrc + ks * 8192;
    lds_load16(smem + w * 1024, as + w * 1024 + lane * 16);
    lds_load16(smem + 4096 + w * 1024, as + 4096 + w * 1024 + lane * 16);
    lds_load16(smem + 8192 + w * 1024, bs + w * 1024 + lane * 16);
    lds_load16(smem + 12288 + w * 1024, bs + 4096 + w * 1024 + lane * 16);
    __syncthreads();

    bf16x8 af[4], bfr[4];
#pragma unroll
    for (int i = 0; i < 4; ++i)
      af[i] = *(const bf16x8*)&lA[(wm * 64 + i * 16 + fr) * 32 + fq * 8];
#pragma unroll
    for (int j = 0; j < 4; ++j)
      bfr[j] = *(const bf16x8*)&lB[(wn * 64 + j * 16 + fr) * 32 + fq * 8];
#pragma unroll
    for (int i = 0; i < 4; ++i)
#pragma unroll
      for (int j = 0; j < 4; ++j)
        acc[i][j] = __builtin_amdgcn_mfma_f32_16x16x32_bf16(af[i], bfr[j], acc[i][j], 0, 0, 0);
    __syncthreads();
  }

  // epilogue: bias + relu + scatter to out rows, coalesced via LDS round-trip.
  float bias[4];
#pragma unroll
  for (int j = 0; j < 4; ++j)
    bias[j] = b2[e * HID + nx * 128 + wn * 64 + j * 16 + fr];

  float* lsf = (float*)smem;                    // per-wave 1024 floats @ w*1024
  int lr = lane >> 2;
#pragma unroll
  for (int i = 0; i < 4; ++i) {
    __syncthreads();
#pragma unroll
    for (int j = 0; j < 4; ++j)
#pragma unroll
      for (int rg = 0; rg < 4; ++rg) {
        float v = acc[i][j][rg] + bias[j];
        lsf[w * 1024 + (fq * 4 + rg) * 64 + j * 16 + fr] = v > 0.f ? v : 0.f;
      }
    __syncthreads();
    int R = wm * 64 + i * 16 + lr;
    if (R < ce - rs) {
      float* orow = out + (size_t)toks[R] * HID + nx * 128 + wn * 64;
#pragma unroll
      for (int s = 0; s < 4; ++s) {
        int ch = (lane & 3) + s * 4;
        *(float4*)(orow + ch * 4) = *(const float4*)&lsf[w * 1024 + lr * 64 + ch * 4];
      }
    }
  }
}

// ---------------- workspace layout (bytes) ----------------
// cnt     @ 0          (32)
// ntiles  @ 128        (4)
// desc    @ 256        (1088)
// idx     @ 4096       (524288)
// W1p     @ 528384     (25165824)
// W2p     @ 25694208   (16777216)
// hp      @ 42471424   (35651584)
// Ap      @ 78123008   (136*48*8192 = 53477376) -> end 131600384 (~131.6 MB)

extern "C" void kernel_launch(void* const* d_in, const int* in_sizes, int n_in,
                              void* d_out, int out_size, void* d_ws, size_t ws_size,
                              hipStream_t stream) {
  const float* x   = (const float*)d_in[0];
  const int*   ops = (const int*)d_in[1];
  const float* emb = (const float*)d_in[2];
  const float* W1  = (const float*)d_in[3];
  const float* b1  = (const float*)d_in[4];
  const float* W2  = (const float*)d_in[5];
  const float* b2  = (const float*)d_in[6];
  float* out = (float*)d_out;

  char* ws = (char*)d_ws;
  int* cnt  = (int*)(ws + 0);
  int* ntp  = (int*)(ws + 128);
  int* desc = (int*)(ws + 256);
  int* idx  = (int*)(ws + 4096);
  short* W1p = (short*)(ws + 528384);
  short* W2p = (short*)(ws + 25694208);
  unsigned short* hp = (unsigned short*)(ws + 42471424);
  short* Ap = (short*)(ws + 78123008);

  hipMemsetAsync(cnt, 0, 32, stream);
  bucket_k<<<BATCH / 256, 256, 0, stream>>>(ops, cnt, idx);
  schedule_k<<<1, 256, 0, stream>>>(cnt, desc, ntp, idx);
  prep_w_k<<<3072 + 2048, 256, 0, stream>>>(W1, W2, W1p, W2p);
  prep_a_k<<<dim3(12, MAXT), 256, 0, stream>>>(x, emb, idx, desc, ntp, Ap);

  dim3 grid(8, MAXT);
  gemm1_k<<<grid, 256, 0, stream>>>(Ap, b1, W1p, hp, desc, ntp);
  gemm2_k<<<grid, 256, 0, stream>>>(hp, b2, W2p, out, idx, cnt, desc, ntp);
}

// Round 3
// 362.772 us; speedup vs baseline: 1.2598x; 1.0499x over previous
//
#include <hip/hip_runtime.h>
#include <hip/hip_bf16.h>

#define BATCH 16384
#define HID   1024
#define EMBD  512
#define NOPS  8
#define MAXT  136   // max tile slots: sum ceil(cnt_e/128) <= 135

typedef __attribute__((ext_vector_type(8))) short bf16x8;
typedef __attribute__((ext_vector_type(4))) float f32x4;

__device__ __forceinline__ unsigned short f2bf(float f) {
  unsigned int u = __float_as_uint(f);
  u += 0x7FFF + ((u >> 16) & 1);
  return (unsigned short)(u >> 16);
}

__device__ __forceinline__ unsigned int pk2(float a, float b) {
  __hip_bfloat162 t = __float22bfloat162_rn(make_float2(a, b));
  return *(unsigned int*)(&t);
}

__device__ __forceinline__ void lds_load16(void* lds, const void* g) {
  __builtin_amdgcn_global_load_lds(
      (const __attribute__((address_space(1))) unsigned int*)g,
      (__attribute__((address_space(3))) unsigned int*)lds, 16, 0, 0);
}

// XCD-locality decode: linear blocks round-robin across 8 XCDs, so bid&7 is
// the XCD. All 8 nx-blocks of a g land on one XCD (A-slab L2 reuse), and each
// XCD covers contiguous g-range [17c, 17c+17) ~= one expert (W-slab in L2).
__device__ __forceinline__ void decode_bid(int bid, int& g, int& nx) {
  g = 17 * (bid & 7) + (bid >> 6);
  nx = (bid >> 3) & 7;
}

// ---------------- phase 0: bucket tokens by expert (wave-aggregated atomics) ----
__global__ void bucket_k(const int* __restrict__ ops, int* __restrict__ cnt,
                         int* __restrict__ idx) {
  int t = blockIdx.x * 256 + threadIdx.x;
  int op = ops[t];
  int lane = threadIdx.x & 63;
#pragma unroll
  for (int o = 0; o < NOPS; ++o) {
    unsigned long long m = __ballot(op == o);
    if (op == o) {
      int leader = __ffsll((unsigned long long)m) - 1;
      int pre = __popcll(m & ((1ull << lane) - 1ull));
      int base = 0;
      if (lane == leader) base = atomicAdd(&cnt[o], __popcll(m));
      base = __shfl(base, leader);
      idx[o * BATCH + base + pre] = t;
    }
  }
}

// build tile descriptors + pad index lists to tile multiples
__global__ void schedule_k(const int* __restrict__ cnt, int* __restrict__ desc,
                           int* __restrict__ ntp, int* __restrict__ idx) {
  if (threadIdx.x == 0) {
    int n = 0;
    for (int e = 0; e < NOPS; ++e) {
      int c = cnt[e];
      for (int t = 0; t < c; t += 128) { desc[2 * n] = e; desc[2 * n + 1] = t; ++n; }
    }
    *ntp = n;
  }
  for (int e = 0; e < NOPS; ++e) {
    int c = cnt[e];
    int cp = (c + 127) & ~127;
    for (int p = c + (int)threadIdx.x; p < cp; p += 256) idx[e * BATCH + p] = 0;
  }
}

// ---------------- phase 1a: convert + transpose + pre-tile weights ----------------
// W1p slab (e, nx, ks): [128 n][32 k] bf16 where value = W1[e][ks*32+k][nx*128+n]
__global__ void prep_w_k(const float* __restrict__ W1, const float* __restrict__ W2,
                         short* __restrict__ W1p, short* __restrict__ W2p) {
  int bid = blockIdx.x;
  const float* W; short* Wp; int ks, nx;
  if (bid < 3072) {               // W1: 8 e * 8 nx * 48 ks
    int e = bid / 384; int r = bid % 384; nx = r / 48; ks = r % 48;
    W = W1 + (size_t)e * 1536 * 1024;
    Wp = W1p + ((size_t)(e * 8 + nx) * 48 + ks) * 4096;
  } else {                        // W2: 8 e * 8 nx * 32 ks
    int b = bid - 3072;
    int e = b / 256; int r = b % 256; nx = r / 32; ks = r % 32;
    W = W2 + (size_t)e * 1024 * 1024;
    Wp = W2p + ((size_t)(e * 8 + nx) * 32 + ks) * 4096;
  }
  __shared__ __align__(16) unsigned short ls[4096];
  int tid = threadIdx.x;
  int nl = (tid & 31) * 4, kl = tid >> 5;     // n base 0..124, k base 0..7
#pragma unroll
  for (int c = 0; c < 4; ++c) {
    int k = kl + c * 8;
    float4 f = *(const float4*)(W + (size_t)(ks * 32 + k) * 1024 + nx * 128 + nl);
    ls[(nl + 0) * 32 + k] = f2bf(f.x);
    ls[(nl + 1) * 32 + k] = f2bf(f.y);
    ls[(nl + 2) * 32 + k] = f2bf(f.z);
    ls[(nl + 3) * 32 + k] = f2bf(f.w);
  }
  __syncthreads();
  uint4* d4 = (uint4*)Wp;
  const uint4* s4 = (const uint4*)ls;
  d4[tid * 2] = s4[tid * 2];
  d4[tid * 2 + 1] = s4[tid * 2 + 1];
}

// ---------------- phase 1b: gather + convert + pre-tile A = [x | emb] ----------
// Ap slab (g, ks): [128 r][32 k] bf16, rows are the tile's gathered tokens.
__global__ void prep_a_k(const float* __restrict__ x, const float* __restrict__ emb,
                         const int* __restrict__ idx, const int* __restrict__ desc,
                         const int* __restrict__ ntp, short* __restrict__ Ap) {
  int g = blockIdx.y;
  if (g >= *ntp) return;
  int e = desc[2 * g], rs = desc[2 * g + 1];
  __shared__ int toks[128];
  int tid = threadIdx.x;
  if (tid < 128) toks[tid] = idx[e * BATCH + rs + tid];
  __syncthreads();
  int r = tid >> 1, ah = tid & 1;
  int tok = toks[r];
  short* dst0 = Ap + (size_t)g * 48 * 4096;
#pragma unroll
  for (int kk = 0; kk < 4; ++kk) {
    int ks = blockIdx.x * 4 + kk;
    const float* src = (ks < 32) ? (x + (size_t)tok * HID + ks * 32 + ah * 16)
                                 : (emb + e * EMBD + (ks - 32) * 32 + ah * 16);
    float4 f0 = ((const float4*)src)[0];
    float4 f1 = ((const float4*)src)[1];
    float4 f2v = ((const float4*)src)[2];
    float4 f3 = ((const float4*)src)[3];
    uint4 p0 = make_uint4(pk2(f0.x, f0.y), pk2(f0.z, f0.w), pk2(f1.x, f1.y), pk2(f1.z, f1.w));
    uint4 p1 = make_uint4(pk2(f2v.x, f2v.y), pk2(f2v.z, f2v.w), pk2(f3.x, f3.y), pk2(f3.z, f3.w));
    short* dst = dst0 + ks * 4096 + r * 32 + ah * 16;
    ((uint4*)dst)[0] = p0;
    ((uint4*)dst)[1] = p1;
  }
}

// ---------------- phase 2: GEMM1  h = relu(A @ W1[e] + b1[e]) ----------------
__global__ __launch_bounds__(256) void gemm1_k(
    const short* __restrict__ Ap, const float* __restrict__ b1,
    const short* __restrict__ W1p, unsigned short* __restrict__ hp,
    const int* __restrict__ desc, const int* __restrict__ ntp) {
  int g, nx;
  decode_bid(blockIdx.x, g, nx);
  if (g >= *ntp) return;
  int e = desc[2 * g];

  __shared__ __align__(16) char smem[16384];
  short* lA = (short*)smem;
  short* lB = (short*)(smem + 8192);

  int tid = threadIdx.x, lane = tid & 63, w = tid >> 6;
  int wm = w >> 1, wn = w & 1;
  int fr = lane & 15, fq = lane >> 4;

  const char* Asrc = (const char*)Ap + (size_t)g * 48 * 8192;
  const char* Bsrc = (const char*)W1p + (size_t)(e * 8 + nx) * 48 * 8192;

  f32x4 acc[4][4] = {};

  for (int ks = 0; ks < 48; ++ks) {
    const char* as = Asrc + ks * 8192;
    const char* bs = Bsrc + ks * 8192;
    lds_load16(smem + w * 1024, as + w * 1024 + lane * 16);
    lds_load16(smem + 4096 + w * 1024, as + 4096 + w * 1024 + lane * 16);
    lds_load16(smem + 8192 + w * 1024, bs + w * 1024 + lane * 16);
    lds_load16(smem + 12288 + w * 1024, bs + 4096 + w * 1024 + lane * 16);
    __syncthreads();

    bf16x8 af[4], bfr[4];
#pragma unroll
    for (int i = 0; i < 4; ++i)
      af[i] = *(const bf16x8*)&lA[(wm * 64 + i * 16 + fr) * 32 + fq * 8];
#pragma unroll
    for (int j = 0; j < 4; ++j)
      bfr[j] = *(const bf16x8*)&lB[(wn * 64 + j * 16 + fr) * 32 + fq * 8];
#pragma unroll
    for (int i = 0; i < 4; ++i)
#pragma unroll
      for (int j = 0; j < 4; ++j)
        acc[i][j] = __builtin_amdgcn_mfma_f32_16x16x32_bf16(af[i], bfr[j], acc[i][j], 0, 0, 0);
    __syncthreads();
  }

  // epilogue: bias + relu + bf16, coalesced via LDS round-trip.
  // hp layout: [g][ks2(32)][128 r][32 k] so gemm2 A-staging is contiguous.
  float bias[4];
#pragma unroll
  for (int j = 0; j < 4; ++j)
    bias[j] = b1[e * HID + nx * 128 + wn * 64 + j * 16 + fr];

  unsigned short* ls = (unsigned short*)smem;   // per-wave 1024 ushorts @ w*1024
  int lr = lane >> 2;
#pragma unroll
  for (int i = 0; i < 4; ++i) {
    __syncthreads();
#pragma unroll
    for (int j = 0; j < 4; ++j)
#pragma unroll
      for (int rg = 0; rg < 4; ++rg) {
        float v = acc[i][j][rg] + bias[j];
        v = v > 0.f ? v : 0.f;
        ls[w * 1024 + (fq * 4 + rg) * 64 + j * 16 + fr] = f2bf(v);
      }
    __syncthreads();
    int R = wm * 64 + i * 16 + lr;
#pragma unroll
    for (int s = 0; s < 2; ++s) {
      int ch = (lane & 3) + s * 4;
      int ks2 = nx * 4 + wn * 2 + (ch >> 2);
      uint4 val = *(const uint4*)&ls[w * 1024 + lr * 64 + ch * 8];
      *(uint4*)(hp + ((size_t)(g * 32 + ks2) * 128 + R) * 32 + (ch & 3) * 8) = val;
    }
  }
}

// ---------------- phase 3: GEMM2  out[tok] = relu(h @ W2[e] + b2[e]) ----------------
__global__ __launch_bounds__(256) void gemm2_k(
    const unsigned short* __restrict__ hp, const float* __restrict__ b2,
    const short* __restrict__ W2p, float* __restrict__ out,
    const int* __restrict__ idx, const int* __restrict__ cnt,
    const int* __restrict__ desc, const int* __restrict__ ntp) {
  int g, nx;
  decode_bid(blockIdx.x, g, nx);
  if (g >= *ntp) return;
  int e = desc[2 * g], rs = desc[2 * g + 1];
  int ce = cnt[e];

  __shared__ __align__(16) char smem[16384];
  __shared__ int toks[128];
  short* lA = (short*)smem;
  short* lB = (short*)(smem + 8192);

  int tid = threadIdx.x, lane = tid & 63, w = tid >> 6;
  int wm = w >> 1, wn = w & 1;
  int fr = lane & 15, fq = lane >> 4;

  if (tid < 128) toks[tid] = idx[e * BATCH + rs + tid];

  const char* Asrc = (const char*)hp + (size_t)g * 32 * 8192;
  const char* Bsrc = (const char*)W2p + (size_t)(e * 8 + nx) * 32 * 8192;

  f32x4 acc[4][4] = {};

  for (int ks = 0; ks < 32; ++ks) {
    const char* as = Asrc + ks * 8192;
    const char* bs = Bsrc + ks * 8192;
    lds_load16(smem + w * 1024, as + w * 1024 + lane * 16);
    lds_load16(smem + 4096 + w * 1024, as + 4096 + w * 1024 + lane * 16);
    lds_load16(smem + 8192 + w * 1024, bs + w * 1024 + lane * 16);
    lds_load16(smem + 12288 + w * 1024, bs + 4096 + w * 1024 + lane * 16);
    __syncthreads();

    bf16x8 af[4], bfr[4];
#pragma unroll
    for (int i = 0; i < 4; ++i)
      af[i] = *(const bf16x8*)&lA[(wm * 64 + i * 16 + fr) * 32 + fq * 8];
#pragma unroll
    for (int j = 0; j < 4; ++j)
      bfr[j] = *(const bf16x8*)&lB[(wn * 64 + j * 16 + fr) * 32 + fq * 8];
#pragma unroll
    for (int i = 0; i < 4; ++i)
#pragma unroll
      for (int j = 0; j < 4; ++j)
        acc[i][j] = __builtin_amdgcn_mfma_f32_16x16x32_bf16(af[i], bfr[j], acc[i][j], 0, 0, 0);
    __syncthreads();
  }

  // epilogue: bias + relu + scatter to out rows, coalesced via LDS round-trip.
  float bias[4];
#pragma unroll
  for (int j = 0; j < 4; ++j)
    bias[j] = b2[e * HID + nx * 128 + wn * 64 + j * 16 + fr];

  float* lsf = (float*)smem;                    // per-wave 1024 floats @ w*1024
  int lr = lane >> 2;
#pragma unroll
  for (int i = 0; i < 4; ++i) {
    __syncthreads();
#pragma unroll
    for (int j = 0; j < 4; ++j)
#pragma unroll
      for (int rg = 0; rg < 4; ++rg) {
        float v = acc[i][j][rg] + bias[j];
        lsf[w * 1024 + (fq * 4 + rg) * 64 + j * 16 + fr] = v > 0.f ? v : 0.f;
      }
    __syncthreads();
    int R = wm * 64 + i * 16 + lr;
    if (R < ce - rs) {
      float* orow = out + (size_t)toks[R] * HID + nx * 128 + wn * 64;
#pragma unroll
      for (int s = 0; s < 4; ++s) {
        int ch = (lane & 3) + s * 4;
        *(float4*)(orow + ch * 4) = *(const float4*)&lsf[w * 1024 + lr * 64 + ch * 4];
      }
    }
  }
}

// ---------------- workspace layout (bytes) ----------------
// cnt     @ 0          (32)
// ntiles  @ 128        (4)
// desc    @ 256        (1088)
// idx     @ 4096       (524288)
// W1p     @ 528384     (25165824)
// W2p     @ 25694208   (16777216)
// hp      @ 42471424   (35651584)
// Ap      @ 78123008   (136*48*8192 = 53477376) -> end 131600384 (~131.6 MB)

extern "C" void kernel_launch(void* const* d_in, const int* in_sizes, int n_in,
                              void* d_out, int out_size, void* d_ws, size_t ws_size,
                              hipStream_t stream) {
  const float* x   = (const float*)d_in[0];
  const int*   ops = (const int*)d_in[1];
  const float* emb = (const float*)d_in[2];
  const float* W1  = (const float*)d_in[3];
  const float* b1  = (const float*)d_in[4];
  const float* W2  = (const float*)d_in[5];
  const float* b2  = (const float*)d_in[6];
  float* out = (float*)d_out;

  char* ws = (char*)d_ws;
  int* cnt  = (int*)(ws + 0);
  int* ntp  = (int*)(ws + 128);
  int* desc = (int*)(ws + 256);
  int* idx  = (int*)(ws + 4096);
  short* W1p = (short*)(ws + 528384);
  short* W2p = (short*)(ws + 25694208);
  unsigned short* hp = (unsigned short*)(ws + 42471424);
  short* Ap = (short*)(ws + 78123008);

  hipMemsetAsync(cnt, 0, 32, stream);
  bucket_k<<<BATCH / 256, 256, 0, stream>>>(ops, cnt, idx);
  schedule_k<<<1, 256, 0, stream>>>(cnt, desc, ntp, idx);
  prep_w_k<<<3072 + 2048, 256, 0, stream>>>(W1, W2, W1p, W2p);
  prep_a_k<<<dim3(12, MAXT), 256, 0, stream>>>(x, emb, idx, desc, ntp, Ap);

  gemm1_k<<<8 * MAXT, 256, 0, stream>>>(Ap, b1, W1p, hp, desc, ntp);
  gemm2_k<<<8 * MAXT, 256, 0, stream>>>(hp, b2, W2p, out, idx, cnt, desc, ntp);
}

// Round 4
// 339.382 us; speedup vs baseline: 1.3466x; 1.0689x over previous
//
#include <hip/hip_runtime.h>
#include <hip/hip_bf16.h>

#define BATCH 16384
#define HID   1024
#define EMBD  512
#define NOPS  8
#define MAXT  136   // max tile slots: sum ceil(cnt_e/128) <= 135
#define CNTS  16    // cnt stride in ints (64 B) — one cache line per expert

typedef __attribute__((ext_vector_type(8))) short bf16x8;
typedef __attribute__((ext_vector_type(4))) float f32x4;

__device__ __forceinline__ unsigned short f2bf(float f) {
  unsigned int u = __float_as_uint(f);
  u += 0x7FFF + ((u >> 16) & 1);
  return (unsigned short)(u >> 16);
}

__device__ __forceinline__ unsigned int pk2(float a, float b) {
  __hip_bfloat162 t = __float22bfloat162_rn(make_float2(a, b));
  return *(unsigned int*)(&t);
}

__device__ __forceinline__ void lds_load16(void* lds, const void* g) {
  __builtin_amdgcn_global_load_lds(
      (const __attribute__((address_space(1))) unsigned int*)g,
      (__attribute__((address_space(3))) unsigned int*)lds, 16, 0, 0);
}

// XCD-locality decode: linear blocks round-robin across 8 XCDs, so bid&7 is
// the XCD. All 8 nx-blocks of a g land on one XCD (A-slab L2 reuse), and each
// XCD covers contiguous g-range [17c, 17c+17) ~= one expert (W-slab in L2).
__device__ __forceinline__ void decode_bid(int bid, int& g, int& nx) {
  g = 17 * (bid & 7) + (bid >> 6);
  nx = (bid >> 3) & 7;
}

// ---------------- phase 0: bucket tokens (block-aggregated atomics) ----------
// Per wave: ballot counts per op; block: 8 atomicAdds on 64B-padded counters.
__global__ void bucket_k(const int* __restrict__ ops, int* __restrict__ cnt,
                         int* __restrict__ idx) {
  __shared__ int wcnt[4][NOPS];
  __shared__ int wbase[4][NOPS];
  int tid = threadIdx.x, lane = tid & 63, w = tid >> 6;
  int t = blockIdx.x * 256 + tid;
  int op = ops[t];
  unsigned long long msave = 0;
#pragma unroll
  for (int o = 0; o < NOPS; ++o) {
    unsigned long long mm = __ballot(op == o);
    if (op == o) msave = mm;
    if (lane == o) wcnt[w][o] = __popcll(mm);
  }
  __syncthreads();
  if (tid < NOPS) {
    int c0 = wcnt[0][tid], c1 = wcnt[1][tid], c2 = wcnt[2][tid], c3 = wcnt[3][tid];
    int base = atomicAdd(&cnt[tid * CNTS], c0 + c1 + c2 + c3);
    wbase[0][tid] = base;
    wbase[1][tid] = base + c0;
    wbase[2][tid] = base + c0 + c1;
    wbase[3][tid] = base + c0 + c1 + c2;
  }
  __syncthreads();
  int pre = __popcll(msave & ((1ull << lane) - 1ull));
  idx[op * BATCH + wbase[w][op] + pre] = t;
}

// build tile descriptors + pad index lists to tile multiples
__global__ void schedule_k(const int* __restrict__ cnt, int* __restrict__ desc,
                           int* __restrict__ ntp, int* __restrict__ idx) {
  if (threadIdx.x == 0) {
    int n = 0;
    for (int e = 0; e < NOPS; ++e) {
      int c = cnt[e * CNTS];
      for (int t = 0; t < c; t += 128) { desc[2 * n] = e; desc[2 * n + 1] = t; ++n; }
    }
    *ntp = n;
  }
  for (int e = 0; e < NOPS; ++e) {
    int c = cnt[e * CNTS];
    int cp = (c + 127) & ~127;
    for (int p = c + (int)threadIdx.x; p < cp; p += 256) idx[e * BATCH + p] = 0;
  }
}

// ---------------- phase 1: merged weight + A-tile prep ----------------
// bid < 5120: weights. W1p slab (e, nx, ks): [128 n][32 k] bf16
//                       where value = W1[e][ks*32+k][nx*128+n]. Same for W2p.
// bid >= 5120: A tiles. Ap slab (g, ks): [128 r][32 k] bf16, gathered tokens.
__global__ void prep_k(const float* __restrict__ W1, const float* __restrict__ W2,
                       short* __restrict__ W1p, short* __restrict__ W2p,
                       const float* __restrict__ x, const float* __restrict__ emb,
                       const int* __restrict__ idx, const int* __restrict__ desc,
                       const int* __restrict__ ntp, short* __restrict__ Ap) {
  __shared__ __align__(16) char sh[8192];
  int bid = blockIdx.x;
  int tid = threadIdx.x;

  if (bid >= 5120) {
    // ---- A-tile path ----
    int bid2 = bid - 5120;
    int g = bid2 / 12, kx = bid2 % 12;
    if (g >= *ntp) return;
    int e = desc[2 * g], rs = desc[2 * g + 1];
    int* toks = (int*)sh;
    if (tid < 128) toks[tid] = idx[e * BATCH + rs + tid];
    __syncthreads();
    int r = tid >> 1, ah = tid & 1;
    int tok = toks[r];
    short* dst0 = Ap + (size_t)g * 48 * 4096;
#pragma unroll
    for (int kk = 0; kk < 4; ++kk) {
      int ks = kx * 4 + kk;
      const float* src = (ks < 32) ? (x + (size_t)tok * HID + ks * 32 + ah * 16)
                                   : (emb + e * EMBD + (ks - 32) * 32 + ah * 16);
      float4 f0 = ((const float4*)src)[0];
      float4 f1 = ((const float4*)src)[1];
      float4 f2v = ((const float4*)src)[2];
      float4 f3 = ((const float4*)src)[3];
      uint4 p0 = make_uint4(pk2(f0.x, f0.y), pk2(f0.z, f0.w), pk2(f1.x, f1.y), pk2(f1.z, f1.w));
      uint4 p1 = make_uint4(pk2(f2v.x, f2v.y), pk2(f2v.z, f2v.w), pk2(f3.x, f3.y), pk2(f3.z, f3.w));
      short* dst = dst0 + ks * 4096 + r * 32 + ah * 16;
      ((uint4*)dst)[0] = p0;
      ((uint4*)dst)[1] = p1;
    }
    return;
  }

  // ---- weight path ----
  const float* W; short* Wp; int ks, nx;
  if (bid < 3072) {               // W1: 8 e * 8 nx * 48 ks
    int e = bid / 384; int r = bid % 384; nx = r / 48; ks = r % 48;
    W = W1 + (size_t)e * 1536 * 1024;
    Wp = W1p + ((size_t)(e * 8 + nx) * 48 + ks) * 4096;
  } else {                        // W2: 8 e * 8 nx * 32 ks
    int b = bid - 3072;
    int e = b / 256; int r = b % 256; nx = r / 32; ks = r % 32;
    W = W2 + (size_t)e * 1024 * 1024;
    Wp = W2p + ((size_t)(e * 8 + nx) * 32 + ks) * 4096;
  }
  unsigned short* ls = (unsigned short*)sh;
  int nl = (tid & 31) * 4, kl = tid >> 5;     // n base 0..124, k base 0..7
#pragma unroll
  for (int c = 0; c < 4; ++c) {
    int k = kl + c * 8;
    float4 f = *(const float4*)(W + (size_t)(ks * 32 + k) * 1024 + nx * 128 + nl);
    ls[(nl + 0) * 32 + k] = f2bf(f.x);
    ls[(nl + 1) * 32 + k] = f2bf(f.y);
    ls[(nl + 2) * 32 + k] = f2bf(f.z);
    ls[(nl + 3) * 32 + k] = f2bf(f.w);
  }
  __syncthreads();
  uint4* d4 = (uint4*)Wp;
  const uint4* s4 = (const uint4*)ls;
  d4[tid * 2] = s4[tid * 2];
  d4[tid * 2 + 1] = s4[tid * 2 + 1];
}

// ---------------- phase 2: GEMM1  h = relu(A @ W1[e] + b1[e]) ----------------
__global__ __launch_bounds__(256) void gemm1_k(
    const short* __restrict__ Ap, const float* __restrict__ b1,
    const short* __restrict__ W1p, unsigned short* __restrict__ hp,
    const int* __restrict__ desc, const int* __restrict__ ntp) {
  int g, nx;
  decode_bid(blockIdx.x, g, nx);
  if (g >= *ntp) return;
  int e = desc[2 * g];

  __shared__ __align__(16) char smem[16384];
  short* lA = (short*)smem;
  short* lB = (short*)(smem + 8192);

  int tid = threadIdx.x, lane = tid & 63, w = tid >> 6;
  int wm = w >> 1, wn = w & 1;
  int fr = lane & 15, fq = lane >> 4;

  const char* Asrc = (const char*)Ap + (size_t)g * 48 * 8192;
  const char* Bsrc = (const char*)W1p + (size_t)(e * 8 + nx) * 48 * 8192;

  f32x4 acc[4][4] = {};

  for (int ks = 0; ks < 48; ++ks) {
    const char* as = Asrc + ks * 8192;
    const char* bs = Bsrc + ks * 8192;
    lds_load16(smem + w * 1024, as + w * 1024 + lane * 16);
    lds_load16(smem + 4096 + w * 1024, as + 4096 + w * 1024 + lane * 16);
    lds_load16(smem + 8192 + w * 1024, bs + w * 1024 + lane * 16);
    lds_load16(smem + 12288 + w * 1024, bs + 4096 + w * 1024 + lane * 16);
    __syncthreads();

    bf16x8 af[4], bfr[4];
#pragma unroll
    for (int i = 0; i < 4; ++i)
      af[i] = *(const bf16x8*)&lA[(wm * 64 + i * 16 + fr) * 32 + fq * 8];
#pragma unroll
    for (int j = 0; j < 4; ++j)
      bfr[j] = *(const bf16x8*)&lB[(wn * 64 + j * 16 + fr) * 32 + fq * 8];
#pragma unroll
    for (int i = 0; i < 4; ++i)
#pragma unroll
      for (int j = 0; j < 4; ++j)
        acc[i][j] = __builtin_amdgcn_mfma_f32_16x16x32_bf16(af[i], bfr[j], acc[i][j], 0, 0, 0);
    __syncthreads();
  }

  // epilogue: bias + relu + bf16, coalesced via LDS round-trip.
  // hp layout: [g][ks2(32)][128 r][32 k] so gemm2 A-staging is contiguous.
  float bias[4];
#pragma unroll
  for (int j = 0; j < 4; ++j)
    bias[j] = b1[e * HID + nx * 128 + wn * 64 + j * 16 + fr];

  unsigned short* ls = (unsigned short*)smem;   // per-wave 1024 ushorts @ w*1024
  int lr = lane >> 2;
#pragma unroll
  for (int i = 0; i < 4; ++i) {
    __syncthreads();
#pragma unroll
    for (int j = 0; j < 4; ++j)
#pragma unroll
      for (int rg = 0; rg < 4; ++rg) {
        float v = acc[i][j][rg] + bias[j];
        v = v > 0.f ? v : 0.f;
        ls[w * 1024 + (fq * 4 + rg) * 64 + j * 16 + fr] = f2bf(v);
      }
    __syncthreads();
    int R = wm * 64 + i * 16 + lr;
#pragma unroll
    for (int s = 0; s < 2; ++s) {
      int ch = (lane & 3) + s * 4;
      int ks2 = nx * 4 + wn * 2 + (ch >> 2);
      uint4 val = *(const uint4*)&ls[w * 1024 + lr * 64 + ch * 8];
      *(uint4*)(hp + ((size_t)(g * 32 + ks2) * 128 + R) * 32 + (ch & 3) * 8) = val;
    }
  }
}

// ---------------- phase 3: GEMM2  out[tok] = relu(h @ W2[e] + b2[e]) ----------------
__global__ __launch_bounds__(256) void gemm2_k(
    const unsigned short* __restrict__ hp, const float* __restrict__ b2,
    const short* __restrict__ W2p, float* __restrict__ out,
    const int* __restrict__ idx, const int* __restrict__ cnt,
    const int* __restrict__ desc, const int* __restrict__ ntp) {
  int g, nx;
  decode_bid(blockIdx.x, g, nx);
  if (g >= *ntp) return;
  int e = desc[2 * g], rs = desc[2 * g + 1];
  int ce = cnt[e * CNTS];

  __shared__ __align__(16) char smem[16384];
  __shared__ int toks[128];
  short* lA = (short*)smem;
  short* lB = (short*)(smem + 8192);

  int tid = threadIdx.x, lane = tid & 63, w = tid >> 6;
  int wm = w >> 1, wn = w & 1;
  int fr = lane & 15, fq = lane >> 4;

  if (tid < 128) toks[tid] = idx[e * BATCH + rs + tid];

  const char* Asrc = (const char*)hp + (size_t)g * 32 * 8192;
  const char* Bsrc = (const char*)W2p + (size_t)(e * 8 + nx) * 32 * 8192;

  f32x4 acc[4][4] = {};

  for (int ks = 0; ks < 32; ++ks) {
    const char* as = Asrc + ks * 8192;
    const char* bs = Bsrc + ks * 8192;
    lds_load16(smem + w * 1024, as + w * 1024 + lane * 16);
    lds_load16(smem + 4096 + w * 1024, as + 4096 + w * 1024 + lane * 16);
    lds_load16(smem + 8192 + w * 1024, bs + w * 1024 + lane * 16);
    lds_load16(smem + 12288 + w * 1024, bs + 4096 + w * 1024 + lane * 16);
    __syncthreads();

    bf16x8 af[4], bfr[4];
#pragma unroll
    for (int i = 0; i < 4; ++i)
      af[i] = *(const bf16x8*)&lA[(wm * 64 + i * 16 + fr) * 32 + fq * 8];
#pragma unroll
    for (int j = 0; j < 4; ++j)
      bfr[j] = *(const bf16x8*)&lB[(wn * 64 + j * 16 + fr) * 32 + fq * 8];
#pragma unroll
    for (int i = 0; i < 4; ++i)
#pragma unroll
      for (int j = 0; j < 4; ++j)
        acc[i][j] = __builtin_amdgcn_mfma_f32_16x16x32_bf16(af[i], bfr[j], acc[i][j], 0, 0, 0);
    __syncthreads();
  }

  // epilogue: bias + relu + scatter to out rows, coalesced via LDS round-trip.
  float bias[4];
#pragma unroll
  for (int j = 0; j < 4; ++j)
    bias[j] = b2[e * HID + nx * 128 + wn * 64 + j * 16 + fr];

  float* lsf = (float*)smem;                    // per-wave 1024 floats @ w*1024
  int lr = lane >> 2;
#pragma unroll
  for (int i = 0; i < 4; ++i) {
    __syncthreads();
#pragma unroll
    for (int j = 0; j < 4; ++j)
#pragma unroll
      for (int rg = 0; rg < 4; ++rg) {
        float v = acc[i][j][rg] + bias[j];
        lsf[w * 1024 + (fq * 4 + rg) * 64 + j * 16 + fr] = v > 0.f ? v : 0.f;
      }
    __syncthreads();
    int R = wm * 64 + i * 16 + lr;
    if (R < ce - rs) {
      float* orow = out + (size_t)toks[R] * HID + nx * 128 + wn * 64;
#pragma unroll
      for (int s = 0; s < 4; ++s) {
        int ch = (lane & 3) + s * 4;
        *(float4*)(orow + ch * 4) = *(const float4*)&lsf[w * 1024 + lr * 64 + ch * 4];
      }
    }
  }
}

// ---------------- workspace layout (bytes) ----------------
// cnt     @ 0          (8*64 = 512, padded 1 line/expert)
// ntiles  @ 1024       (4)
// desc    @ 1280       (1088)
// idx     @ 4096       (524288)
// W1p     @ 528384     (25165824)
// W2p     @ 25694208   (16777216)
// hp      @ 42471424   (35651584)
// Ap      @ 78123008   (136*48*8192 = 53477376) -> end 131600384 (~131.6 MB)

extern "C" void kernel_launch(void* const* d_in, const int* in_sizes, int n_in,
                              void* d_out, int out_size, void* d_ws, size_t ws_size,
                              hipStream_t stream) {
  const float* x   = (const float*)d_in[0];
  const int*   ops = (const int*)d_in[1];
  const float* emb = (const float*)d_in[2];
  const float* W1  = (const float*)d_in[3];
  const float* b1  = (const float*)d_in[4];
  const float* W2  = (const float*)d_in[5];
  const float* b2  = (const float*)d_in[6];
  float* out = (float*)d_out;

  char* ws = (char*)d_ws;
  int* cnt  = (int*)(ws + 0);
  int* ntp  = (int*)(ws + 1024);
  int* desc = (int*)(ws + 1280);
  int* idx  = (int*)(ws + 4096);
  short* W1p = (short*)(ws + 528384);
  short* W2p = (short*)(ws + 25694208);
  unsigned short* hp = (unsigned short*)(ws + 42471424);
  short* Ap = (short*)(ws + 78123008);

  hipMemsetAsync(cnt, 0, 512, stream);
  bucket_k<<<BATCH / 256, 256, 0, stream>>>(ops, cnt, idx);
  schedule_k<<<1, 256, 0, stream>>>(cnt, desc, ntp, idx);
  prep_k<<<5120 + 12 * MAXT, 256, 0, stream>>>(W1, W2, W1p, W2p,
                                               x, emb, idx, desc, ntp, Ap);
  gemm1_k<<<8 * MAXT, 256, 0, stream>>>(Ap, b1, W1p, hp, desc, ntp);
  gemm2_k<<<8 * MAXT, 256, 0, stream>>>(hp, b2, W2p, out, idx, cnt, desc, ntp);
}

// Round 5
// 338.889 us; speedup vs baseline: 1.3486x; 1.0015x over previous
//
#include <hip/hip_runtime.h>
#include <hip/hip_bf16.h>

#define BATCH 16384
#define HID   1024
#define EMBD  512
#define NOPS  8
#define MAXT  136   // max tile slots: sum ceil(cnt_e/128) <= 135
#define CNTS  16    // cnt stride in ints (64 B) — one cache line per expert

typedef __attribute__((ext_vector_type(8))) short bf16x8;
typedef __attribute__((ext_vector_type(4))) float f32x4;

__device__ __forceinline__ unsigned short f2bf(float f) {
  unsigned int u = __float_as_uint(f);
  u += 0x7FFF + ((u >> 16) & 1);
  return (unsigned short)(u >> 16);
}

__device__ __forceinline__ unsigned int pk2(float a, float b) {
  __hip_bfloat162 t = __float22bfloat162_rn(make_float2(a, b));
  return *(unsigned int*)(&t);
}

__device__ __forceinline__ void lds_load16(void* lds, const void* g) {
  __builtin_amdgcn_global_load_lds(
      (const __attribute__((address_space(1))) unsigned int*)g,
      (__attribute__((address_space(3))) unsigned int*)lds, 16, 0, 0);
}

// XCD-locality decode: linear blocks round-robin across 8 XCDs, so bid&7 is
// the XCD. All 8 nx-blocks of a g land on one XCD (A-slab L2 reuse), and each
// XCD covers contiguous g-range [17c, 17c+17) ~= one expert (W-slab in L2).
__device__ __forceinline__ void decode_bid(int bid, int& g, int& nx) {
  g = 17 * (bid & 7) + (bid >> 6);
  nx = (bid >> 3) & 7;
}

// ---------------- phase 0: bucket tokens (block-aggregated atomics) ----------
__global__ void bucket_k(const int* __restrict__ ops, int* __restrict__ cnt,
                         int* __restrict__ idx) {
  __shared__ int wcnt[4][NOPS];
  __shared__ int wbase[4][NOPS];
  int tid = threadIdx.x, lane = tid & 63, w = tid >> 6;
  int t = blockIdx.x * 256 + tid;
  int op = ops[t];
  unsigned long long msave = 0;
#pragma unroll
  for (int o = 0; o < NOPS; ++o) {
    unsigned long long mm = __ballot(op == o);
    if (op == o) msave = mm;
    if (lane == o) wcnt[w][o] = __popcll(mm);
  }
  __syncthreads();
  if (tid < NOPS) {
    int c0 = wcnt[0][tid], c1 = wcnt[1][tid], c2 = wcnt[2][tid], c3 = wcnt[3][tid];
    int base = atomicAdd(&cnt[tid * CNTS], c0 + c1 + c2 + c3);
    wbase[0][tid] = base;
    wbase[1][tid] = base + c0;
    wbase[2][tid] = base + c0 + c1;
    wbase[3][tid] = base + c0 + c1 + c2;
  }
  __syncthreads();
  int pre = __popcll(msave & ((1ull << lane) - 1ull));
  idx[op * BATCH + wbase[w][op] + pre] = t;
}

// build tile descriptors + pad index lists to tile multiples
__global__ void schedule_k(const int* __restrict__ cnt, int* __restrict__ desc,
                           int* __restrict__ ntp, int* __restrict__ idx) {
  if (threadIdx.x == 0) {
    int n = 0;
    for (int e = 0; e < NOPS; ++e) {
      int c = cnt[e * CNTS];
      for (int t = 0; t < c; t += 128) { desc[2 * n] = e; desc[2 * n + 1] = t; ++n; }
    }
    *ntp = n;
  }
  for (int e = 0; e < NOPS; ++e) {
    int c = cnt[e * CNTS];
    int cp = (c + 127) & ~127;
    for (int p = c + (int)threadIdx.x; p < cp; p += 256) idx[e * BATCH + p] = 0;
  }
}

// ---------------- phase 1: merged weight + A-tile prep ----------------
// bid < 5120: weights, LDS-free transpose. W1p slab (e, nx, ks): [128 n][32 k]
//   bf16 where value = W1[e][ks*32+k][nx*128+n]. Same for W2p.
//   Lane reads along contiguous n (coalesced 256B/instr), 16 strided k-loads,
//   packs bf16 in regs, writes its 32-k row chunk as two uint4.
// bid >= 5120: A tiles. Ap slab (g, ks): [128 r][32 k] bf16, gathered tokens.
__global__ void prep_k(const float* __restrict__ W1, const float* __restrict__ W2,
                       short* __restrict__ W1p, short* __restrict__ W2p,
                       const float* __restrict__ x, const float* __restrict__ emb,
                       const int* __restrict__ idx, const int* __restrict__ desc,
                       const int* __restrict__ ntp, short* __restrict__ Ap) {
  int bid = blockIdx.x;
  int tid = threadIdx.x;

  if (bid >= 5120) {
    // ---- A-tile path ----
    __shared__ int toks[128];
    int bid2 = bid - 5120;
    int g = bid2 / 12, kx = bid2 % 12;
    if (g >= *ntp) return;
    int e = desc[2 * g], rs = desc[2 * g + 1];
    if (tid < 128) toks[tid] = idx[e * BATCH + rs + tid];
    __syncthreads();
    int r = tid >> 1, ah = tid & 1;
    int tok = toks[r];
    short* dst0 = Ap + (size_t)g * 48 * 4096;
#pragma unroll
    for (int kk = 0; kk < 4; ++kk) {
      int ks = kx * 4 + kk;
      const float* src = (ks < 32) ? (x + (size_t)tok * HID + ks * 32 + ah * 16)
                                   : (emb + e * EMBD + (ks - 32) * 32 + ah * 16);
      float4 f0 = ((const float4*)src)[0];
      float4 f1 = ((const float4*)src)[1];
      float4 f2v = ((const float4*)src)[2];
      float4 f3 = ((const float4*)src)[3];
      uint4 p0 = make_uint4(pk2(f0.x, f0.y), pk2(f0.z, f0.w), pk2(f1.x, f1.y), pk2(f1.z, f1.w));
      uint4 p1 = make_uint4(pk2(f2v.x, f2v.y), pk2(f2v.z, f2v.w), pk2(f3.x, f3.y), pk2(f3.z, f3.w));
      short* dst = dst0 + ks * 4096 + r * 32 + ah * 16;
      ((uint4*)dst)[0] = p0;
      ((uint4*)dst)[1] = p1;
    }
    return;
  }

  // ---- weight path (LDS-free) ----
  const float* W; short* Wp; int ks, nx;
  if (bid < 3072) {               // W1: 8 e * 8 nx * 48 ks
    int e = bid / 384; int r = bid % 384; nx = r / 48; ks = r % 48;
    W = W1 + (size_t)e * 1536 * 1024;
    Wp = W1p + ((size_t)(e * 8 + nx) * 48 + ks) * 4096;
  } else {                        // W2: 8 e * 8 nx * 32 ks
    int b = bid - 3072;
    int e = b / 256; int r = b % 256; nx = r / 32; ks = r % 32;
    W = W2 + (size_t)e * 1024 * 1024;
    Wp = W2p + ((size_t)(e * 8 + nx) * 32 + ks) * 4096;
  }
  int n = tid & 127, kh = tid >> 7;           // kh: low/high 16 of the 32-k tile
  const float* src = W + (size_t)(ks * 32 + kh * 16) * 1024 + nx * 128 + n;
  float v[16];
#pragma unroll
  for (int kk = 0; kk < 16; ++kk) v[kk] = src[(size_t)kk * 1024];
  uint4 a, b;
  a.x = pk2(v[0], v[1]);  a.y = pk2(v[2], v[3]);
  a.z = pk2(v[4], v[5]);  a.w = pk2(v[6], v[7]);
  b.x = pk2(v[8], v[9]);  b.y = pk2(v[10], v[11]);
  b.z = pk2(v[12], v[13]); b.w = pk2(v[14], v[15]);
  uint4* dst = (uint4*)(Wp + (size_t)n * 32);
  dst[kh * 2] = a;
  dst[kh * 2 + 1] = b;
}

// ---------------- phase 2: GEMM1  h = relu(A @ W1[e] + b1[e]) ----------------
__global__ __launch_bounds__(256) void gemm1_k(
    const short* __restrict__ Ap, const float* __restrict__ b1,
    const short* __restrict__ W1p, unsigned short* __restrict__ hp,
    const int* __restrict__ desc, const int* __restrict__ ntp) {
  int g, nx;
  decode_bid(blockIdx.x, g, nx);
  if (g >= *ntp) return;
  int e = desc[2 * g];

  __shared__ __align__(16) char smem[16384];
  short* lA = (short*)smem;
  short* lB = (short*)(smem + 8192);

  int tid = threadIdx.x, lane = tid & 63, w = tid >> 6;
  int wm = w >> 1, wn = w & 1;
  int fr = lane & 15, fq = lane >> 4;

  const char* Asrc = (const char*)Ap + (size_t)g * 48 * 8192;
  const char* Bsrc = (const char*)W1p + (size_t)(e * 8 + nx) * 48 * 8192;

  f32x4 acc[4][4] = {};

  for (int ks = 0; ks < 48; ++ks) {
    const char* as = Asrc + ks * 8192;
    const char* bs = Bsrc + ks * 8192;
    lds_load16(smem + w * 1024, as + w * 1024 + lane * 16);
    lds_load16(smem + 4096 + w * 1024, as + 4096 + w * 1024 + lane * 16);
    lds_load16(smem + 8192 + w * 1024, bs + w * 1024 + lane * 16);
    lds_load16(smem + 12288 + w * 1024, bs + 4096 + w * 1024 + lane * 16);
    __syncthreads();

    bf16x8 af[4], bfr[4];
#pragma unroll
    for (int i = 0; i < 4; ++i)
      af[i] = *(const bf16x8*)&lA[(wm * 64 + i * 16 + fr) * 32 + fq * 8];
#pragma unroll
    for (int j = 0; j < 4; ++j)
      bfr[j] = *(const bf16x8*)&lB[(wn * 64 + j * 16 + fr) * 32 + fq * 8];
#pragma unroll
    for (int i = 0; i < 4; ++i)
#pragma unroll
      for (int j = 0; j < 4; ++j)
        acc[i][j] = __builtin_amdgcn_mfma_f32_16x16x32_bf16(af[i], bfr[j], acc[i][j], 0, 0, 0);
    __syncthreads();
  }

  // epilogue: bias + relu + bf16, coalesced via LDS round-trip.
  // hp layout: [g][ks2(32)][128 r][32 k] so gemm2 A-staging is contiguous.
  float bias[4];
#pragma unroll
  for (int j = 0; j < 4; ++j)
    bias[j] = b1[e * HID + nx * 128 + wn * 64 + j * 16 + fr];

  unsigned short* ls = (unsigned short*)smem;   // per-wave 1024 ushorts @ w*1024
  int lr = lane >> 2;
#pragma unroll
  for (int i = 0; i < 4; ++i) {
    __syncthreads();
#pragma unroll
    for (int j = 0; j < 4; ++j)
#pragma unroll
      for (int rg = 0; rg < 4; ++rg) {
        float v = acc[i][j][rg] + bias[j];
        v = v > 0.f ? v : 0.f;
        ls[w * 1024 + (fq * 4 + rg) * 64 + j * 16 + fr] = f2bf(v);
      }
    __syncthreads();
    int R = wm * 64 + i * 16 + lr;
#pragma unroll
    for (int s = 0; s < 2; ++s) {
      int ch = (lane & 3) + s * 4;
      int ks2 = nx * 4 + wn * 2 + (ch >> 2);
      uint4 val = *(const uint4*)&ls[w * 1024 + lr * 64 + ch * 8];
      *(uint4*)(hp + ((size_t)(g * 32 + ks2) * 128 + R) * 32 + (ch & 3) * 8) = val;
    }
  }
}

// ---------------- phase 3: GEMM2  out[tok] = relu(h @ W2[e] + b2[e]) ----------------
__global__ __launch_bounds__(256) void gemm2_k(
    const unsigned short* __restrict__ hp, const float* __restrict__ b2,
    const short* __restrict__ W2p, float* __restrict__ out,
    const int* __restrict__ idx, const int* __restrict__ cnt,
    const int* __restrict__ desc, const int* __restrict__ ntp) {
  int g, nx;
  decode_bid(blockIdx.x, g, nx);
  if (g >= *ntp) return;
  int e = desc[2 * g], rs = desc[2 * g + 1];
  int ce = cnt[e * CNTS];

  __shared__ __align__(16) char smem[16384];
  __shared__ int toks[128];
  short* lA = (short*)smem;
  short* lB = (short*)(smem + 8192);

  int tid = threadIdx.x, lane = tid & 63, w = tid >> 6;
  int wm = w >> 1, wn = w & 1;
  int fr = lane & 15, fq = lane >> 4;

  if (tid < 128) toks[tid] = idx[e * BATCH + rs + tid];

  const char* Asrc = (const char*)hp + (size_t)g * 32 * 8192;
  const char* Bsrc = (const char*)W2p + (size_t)(e * 8 + nx) * 32 * 8192;

  f32x4 acc[4][4] = {};

  for (int ks = 0; ks < 32; ++ks) {
    const char* as = Asrc + ks * 8192;
    const char* bs = Bsrc + ks * 8192;
    lds_load16(smem + w * 1024, as + w * 1024 + lane * 16);
    lds_load16(smem + 4096 + w * 1024, as + 4096 + w * 1024 + lane * 16);
    lds_load16(smem + 8192 + w * 1024, bs + w * 1024 + lane * 16);
    lds_load16(smem + 12288 + w * 1024, bs + 4096 + w * 1024 + lane * 16);
    __syncthreads();

    bf16x8 af[4], bfr[4];
#pragma unroll
    for (int i = 0; i < 4; ++i)
      af[i] = *(const bf16x8*)&lA[(wm * 64 + i * 16 + fr) * 32 + fq * 8];
#pragma unroll
    for (int j = 0; j < 4; ++j)
      bfr[j] = *(const bf16x8*)&lB[(wn * 64 + j * 16 + fr) * 32 + fq * 8];
#pragma unroll
    for (int i = 0; i < 4; ++i)
#pragma unroll
      for (int j = 0; j < 4; ++j)
        acc[i][j] = __builtin_amdgcn_mfma_f32_16x16x32_bf16(af[i], bfr[j], acc[i][j], 0, 0, 0);
    __syncthreads();
  }

  // epilogue: bias + relu + scatter to out rows, coalesced via LDS round-trip.
  float bias[4];
#pragma unroll
  for (int j = 0; j < 4; ++j)
    bias[j] = b2[e * HID + nx * 128 + wn * 64 + j * 16 + fr];

  float* lsf = (float*)smem;                    // per-wave 1024 floats @ w*1024
  int lr = lane >> 2;
#pragma unroll
  for (int i = 0; i < 4; ++i) {
    __syncthreads();
#pragma unroll
    for (int j = 0; j < 4; ++j)
#pragma unroll
      for (int rg = 0; rg < 4; ++rg) {
        float v = acc[i][j][rg] + bias[j];
        lsf[w * 1024 + (fq * 4 + rg) * 64 + j * 16 + fr] = v > 0.f ? v : 0.f;
      }
    __syncthreads();
    int R = wm * 64 + i * 16 + lr;
    if (R < ce - rs) {
      float* orow = out + (size_t)toks[R] * HID + nx * 128 + wn * 64;
#pragma unroll
      for (int s = 0; s < 4; ++s) {
        int ch = (lane & 3) + s * 4;
        *(float4*)(orow + ch * 4) = *(const float4*)&lsf[w * 1024 + lr * 64 + ch * 4];
      }
    }
  }
}

// ---------------- workspace layout (bytes) ----------------
// cnt     @ 0          (8*64 = 512, padded 1 line/expert)
// ntiles  @ 1024       (4)
// desc    @ 1280       (1088)
// idx     @ 4096       (524288)
// W1p     @ 528384     (25165824)
// W2p     @ 25694208   (16777216)
// hp      @ 42471424   (35651584)
// Ap      @ 78123008   (136*48*8192 = 53477376) -> end 131600384 (~131.6 MB)

extern "C" void kernel_launch(void* const* d_in, const int* in_sizes, int n_in,
                              void* d_out, int out_size, void* d_ws, size_t ws_size,
                              hipStream_t stream) {
  const float* x   = (const float*)d_in[0];
  const int*   ops = (const int*)d_in[1];
  const float* emb = (const float*)d_in[2];
  const float* W1  = (const float*)d_in[3];
  const float* b1  = (const float*)d_in[4];
  const float* W2  = (const float*)d_in[5];
  const float* b2  = (const float*)d_in[6];
  float* out = (float*)d_out;

  char* ws = (char*)d_ws;
  int* cnt  = (int*)(ws + 0);
  int* ntp  = (int*)(ws + 1024);
  int* desc = (int*)(ws + 1280);
  int* idx  = (int*)(ws + 4096);
  short* W1p = (short*)(ws + 528384);
  short* W2p = (short*)(ws + 25694208);
  unsigned short* hp = (unsigned short*)(ws + 42471424);
  short* Ap = (short*)(ws + 78123008);

  hipMemsetAsync(cnt, 0, 512, stream);
  bucket_k<<<BATCH / 256, 256, 0, stream>>>(ops, cnt, idx);
  schedule_k<<<1, 256, 0, stream>>>(cnt, desc, ntp, idx);
  prep_k<<<5120 + 12 * MAXT, 256, 0, stream>>>(W1, W2, W1p, W2p,
                                               x, emb, idx, desc, ntp, Ap);
  gemm1_k<<<8 * MAXT, 256, 0, stream>>>(Ap, b1, W1p, hp, desc, ntp);
  gemm2_k<<<8 * MAXT, 256, 0, stream>>>(hp, b2, W2p, out, idx, cnt, desc, ntp);
}

// Round 6
// 325.014 us; speedup vs baseline: 1.4061x; 1.0427x over previous
//
#include <hip/hip_runtime.h>
#include <hip/hip_bf16.h>

#define BATCH 16384
#define HID   1024
#define EMBD  512
#define NOPS  8
#define MAXT  136   // max tile slots: sum ceil(cnt_e/128) <= 135
#define CNTS  16    // cnt stride in ints (64 B) — one cache line per expert

typedef __attribute__((ext_vector_type(8))) short bf16x8;
typedef __attribute__((ext_vector_type(4))) float f32x4;

__device__ __forceinline__ unsigned short f2bf(float f) {
  unsigned int u = __float_as_uint(f);
  u += 0x7FFF + ((u >> 16) & 1);
  return (unsigned short)(u >> 16);
}

__device__ __forceinline__ unsigned int pk2(float a, float b) {
  __hip_bfloat162 t = __float22bfloat162_rn(make_float2(a, b));
  return *(unsigned int*)(&t);
}

__device__ __forceinline__ void lds_load16(void* lds, const void* g) {
  __builtin_amdgcn_global_load_lds(
      (const __attribute__((address_space(1))) unsigned int*)g,
      (__attribute__((address_space(3))) unsigned int*)lds, 16, 0, 0);
}

// XCD-locality decode: linear blocks round-robin across 8 XCDs, so bid&7 is
// the XCD. All 8 nx-blocks of a g land on one XCD (A-slab L2 reuse), and each
// XCD covers contiguous g-range [17c, 17c+17) ~= one expert (W-slab in L2).
__device__ __forceinline__ void decode_bid(int bid, int& g, int& nx) {
  g = 17 * (bid & 7) + (bid >> 6);
  nx = (bid >> 3) & 7;
}

// LDS-free weight transpose tile: lane reads along contiguous n (coalesced),
// 16 strided k-loads, packs bf16 in regs, writes 32-k half-row as two uint4.
// Wp slab: [128 n][32 k] bf16 where value = W[ks*32+k][nx*128+n].
__device__ __forceinline__ void w_prep_tile(const float* __restrict__ W,
                                            short* __restrict__ Wp,
                                            int ks, int nx, int tid) {
  int n = tid & 127, kh = tid >> 7;           // kh: low/high 16 of the 32-k tile
  const float* src = W + (size_t)(ks * 32 + kh * 16) * 1024 + nx * 128 + n;
  float v[16];
#pragma unroll
  for (int kk = 0; kk < 16; ++kk) v[kk] = src[(size_t)kk * 1024];
  uint4 a, b;
  a.x = pk2(v[0], v[1]);  a.y = pk2(v[2], v[3]);
  a.z = pk2(v[4], v[5]);  a.w = pk2(v[6], v[7]);
  b.x = pk2(v[8], v[9]);  b.y = pk2(v[10], v[11]);
  b.z = pk2(v[12], v[13]); b.w = pk2(v[14], v[15]);
  uint4* dst = (uint4*)(Wp + (size_t)n * 32);
  dst[kh * 2] = a;
  dst[kh * 2 + 1] = b;
}

// ---------------- phase 0: bucket (64 blocks) + W1 prep (3072 blocks) --------
// Independent work fused into one launch so W1 conversion overlaps bucketing.
__global__ void bucket_w1_k(const int* __restrict__ ops, int* __restrict__ cnt,
                            int* __restrict__ idx, const float* __restrict__ W1,
                            short* __restrict__ W1p) {
  int bid = blockIdx.x;
  int tid = threadIdx.x;
  if (bid >= 64) {
    // ---- W1 path: 8 e * 8 nx * 48 ks ----
    int b = bid - 64;
    int e = b / 384; int r = b % 384; int nx = r / 48, ks = r % 48;
    w_prep_tile(W1 + (size_t)e * 1536 * 1024,
                W1p + ((size_t)(e * 8 + nx) * 48 + ks) * 4096, ks, nx, tid);
    return;
  }
  // ---- bucket path (block-aggregated atomics) ----
  __shared__ int wcnt[4][NOPS];
  __shared__ int wbase[4][NOPS];
  int lane = tid & 63, w = tid >> 6;
  int t = bid * 256 + tid;
  int op = ops[t];
  unsigned long long msave = 0;
#pragma unroll
  for (int o = 0; o < NOPS; ++o) {
    unsigned long long mm = __ballot(op == o);
    if (op == o) msave = mm;
    if (lane == o) wcnt[w][o] = __popcll(mm);
  }
  __syncthreads();
  if (tid < NOPS) {
    int c0 = wcnt[0][tid], c1 = wcnt[1][tid], c2 = wcnt[2][tid], c3 = wcnt[3][tid];
    int base = atomicAdd(&cnt[tid * CNTS], c0 + c1 + c2 + c3);
    wbase[0][tid] = base;
    wbase[1][tid] = base + c0;
    wbase[2][tid] = base + c0 + c1;
    wbase[3][tid] = base + c0 + c1 + c2;
  }
  __syncthreads();
  int pre = __popcll(msave & ((1ull << lane) - 1ull));
  idx[op * BATCH + wbase[w][op] + pre] = t;
}

// build tile descriptors + pad index lists to tile multiples
__global__ void schedule_k(const int* __restrict__ cnt, int* __restrict__ desc,
                           int* __restrict__ ntp, int* __restrict__ idx) {
  if (threadIdx.x == 0) {
    int n = 0;
    for (int e = 0; e < NOPS; ++e) {
      int c = cnt[e * CNTS];
      for (int t = 0; t < c; t += 128) { desc[2 * n] = e; desc[2 * n + 1] = t; ++n; }
    }
    *ntp = n;
  }
  for (int e = 0; e < NOPS; ++e) {
    int c = cnt[e * CNTS];
    int cp = (c + 127) & ~127;
    for (int p = c + (int)threadIdx.x; p < cp; p += 256) idx[e * BATCH + p] = 0;
  }
}

// ---------------- phase 1: gather + convert + pre-tile A = [x | emb] ----------
// Ap slab (g, ks): [128 r][32 k] bf16, rows are the tile's gathered tokens.
__global__ void prep_a_k(const float* __restrict__ x, const float* __restrict__ emb,
                         const int* __restrict__ idx, const int* __restrict__ desc,
                         const int* __restrict__ ntp, short* __restrict__ Ap) {
  __shared__ int toks[128];
  int bid = blockIdx.x;
  int g = bid / 12, kx = bid % 12;
  if (g >= *ntp) return;
  int e = desc[2 * g], rs = desc[2 * g + 1];
  int tid = threadIdx.x;
  if (tid < 128) toks[tid] = idx[e * BATCH + rs + tid];
  __syncthreads();
  int r = tid >> 1, ah = tid & 1;
  int tok = toks[r];
  short* dst0 = Ap + (size_t)g * 48 * 4096;
#pragma unroll
  for (int kk = 0; kk < 4; ++kk) {
    int ks = kx * 4 + kk;
    const float* src = (ks < 32) ? (x + (size_t)tok * HID + ks * 32 + ah * 16)
                                 : (emb + e * EMBD + (ks - 32) * 32 + ah * 16);
    float4 f0 = ((const float4*)src)[0];
    float4 f1 = ((const float4*)src)[1];
    float4 f2v = ((const float4*)src)[2];
    float4 f3 = ((const float4*)src)[3];
    uint4 p0 = make_uint4(pk2(f0.x, f0.y), pk2(f0.z, f0.w), pk2(f1.x, f1.y), pk2(f1.z, f1.w));
    uint4 p1 = make_uint4(pk2(f2v.x, f2v.y), pk2(f2v.z, f2v.w), pk2(f3.x, f3.y), pk2(f3.z, f3.w));
    short* dst = dst0 + ks * 4096 + r * 32 + ah * 16;
    ((uint4*)dst)[0] = p0;
    ((uint4*)dst)[1] = p1;
  }
}

// ---------------- phase 2: GEMM1 (1088 blocks) + W2 prep (2048 blocks) -------
// W2 conversion is memory-only work co-resident with gemm1's MFMA waves (they
// use different pipes — overlap is ~free). W2p is complete when this kernel
// retires, i.e. before gemm2 launches.
__global__ __launch_bounds__(256) void gemm1_w2_k(
    const short* __restrict__ Ap, const float* __restrict__ b1,
    const short* __restrict__ W1p, unsigned short* __restrict__ hp,
    const int* __restrict__ desc, const int* __restrict__ ntp,
    const float* __restrict__ W2, short* __restrict__ W2p) {
  int bid = blockIdx.x;
  int tid = threadIdx.x;
  if (bid >= 8 * MAXT) {
    // ---- W2 path: 8 e * 8 nx * 32 ks ----
    int b = bid - 8 * MAXT;
    int e = b / 256; int r = b % 256; int nx = r / 32, ks = r % 32;
    w_prep_tile(W2 + (size_t)e * 1024 * 1024,
                W2p + ((size_t)(e * 8 + nx) * 32 + ks) * 4096, ks, nx, tid);
    return;
  }
  int g, nx;
  decode_bid(bid, g, nx);
  if (g >= *ntp) return;
  int e = desc[2 * g];

  __shared__ __align__(16) char smem[16384];
  short* lA = (short*)smem;
  short* lB = (short*)(smem + 8192);

  int lane = tid & 63, w = tid >> 6;
  int wm = w >> 1, wn = w & 1;
  int fr = lane & 15, fq = lane >> 4;

  const char* Asrc = (const char*)Ap + (size_t)g * 48 * 8192;
  const char* Bsrc = (const char*)W1p + (size_t)(e * 8 + nx) * 48 * 8192;

  f32x4 acc[4][4] = {};

  for (int ks = 0; ks < 48; ++ks) {
    const char* as = Asrc + ks * 8192;
    const char* bs = Bsrc + ks * 8192;
    lds_load16(smem + w * 1024, as + w * 1024 + lane * 16);
    lds_load16(smem + 4096 + w * 1024, as + 4096 + w * 1024 + lane * 16);
    lds_load16(smem + 8192 + w * 1024, bs + w * 1024 + lane * 16);
    lds_load16(smem + 12288 + w * 1024, bs + 4096 + w * 1024 + lane * 16);
    __syncthreads();

    bf16x8 af[4], bfr[4];
#pragma unroll
    for (int i = 0; i < 4; ++i)
      af[i] = *(const bf16x8*)&lA[(wm * 64 + i * 16 + fr) * 32 + fq * 8];
#pragma unroll
    for (int j = 0; j < 4; ++j)
      bfr[j] = *(const bf16x8*)&lB[(wn * 64 + j * 16 + fr) * 32 + fq * 8];
#pragma unroll
    for (int i = 0; i < 4; ++i)
#pragma unroll
      for (int j = 0; j < 4; ++j)
        acc[i][j] = __builtin_amdgcn_mfma_f32_16x16x32_bf16(af[i], bfr[j], acc[i][j], 0, 0, 0);
    __syncthreads();
  }

  // epilogue: bias + relu + bf16, coalesced via LDS round-trip.
  // hp layout: [g][ks2(32)][128 r][32 k] so gemm2 A-staging is contiguous.
  float bias[4];
#pragma unroll
  for (int j = 0; j < 4; ++j)
    bias[j] = b1[e * HID + nx * 128 + wn * 64 + j * 16 + fr];

  unsigned short* ls = (unsigned short*)smem;   // per-wave 1024 ushorts @ w*1024
  int lr = lane >> 2;
#pragma unroll
  for (int i = 0; i < 4; ++i) {
    __syncthreads();
#pragma unroll
    for (int j = 0; j < 4; ++j)
#pragma unroll
      for (int rg = 0; rg < 4; ++rg) {
        float v = acc[i][j][rg] + bias[j];
        v = v > 0.f ? v : 0.f;
        ls[w * 1024 + (fq * 4 + rg) * 64 + j * 16 + fr] = f2bf(v);
      }
    __syncthreads();
    int R = wm * 64 + i * 16 + lr;
#pragma unroll
    for (int s = 0; s < 2; ++s) {
      int ch = (lane & 3) + s * 4;
      int ks2 = nx * 4 + wn * 2 + (ch >> 2);
      uint4 val = *(const uint4*)&ls[w * 1024 + lr * 64 + ch * 8];
      *(uint4*)(hp + ((size_t)(g * 32 + ks2) * 128 + R) * 32 + (ch & 3) * 8) = val;
    }
  }
}

// ---------------- phase 3: GEMM2  out[tok] = relu(h @ W2[e] + b2[e]) ----------------
__global__ __launch_bounds__(256) void gemm2_k(
    const unsigned short* __restrict__ hp, const float* __restrict__ b2,
    const short* __restrict__ W2p, float* __restrict__ out,
    const int* __restrict__ idx, const int* __restrict__ cnt,
    const int* __restrict__ desc, const int* __restrict__ ntp) {
  int g, nx;
  decode_bid(blockIdx.x, g, nx);
  if (g >= *ntp) return;
  int e = desc[2 * g], rs = desc[2 * g + 1];
  int ce = cnt[e * CNTS];

  __shared__ __align__(16) char smem[16384];
  __shared__ int toks[128];
  short* lA = (short*)smem;
  short* lB = (short*)(smem + 8192);

  int tid = threadIdx.x, lane = tid & 63, w = tid >> 6;
  int wm = w >> 1, wn = w & 1;
  int fr = lane & 15, fq = lane >> 4;

  if (tid < 128) toks[tid] = idx[e * BATCH + rs + tid];

  const char* Asrc = (const char*)hp + (size_t)g * 32 * 8192;
  const char* Bsrc = (const char*)W2p + (size_t)(e * 8 + nx) * 32 * 8192;

  f32x4 acc[4][4] = {};

  for (int ks = 0; ks < 32; ++ks) {
    const char* as = Asrc + ks * 8192;
    const char* bs = Bsrc + ks * 8192;
    lds_load16(smem + w * 1024, as + w * 1024 + lane * 16);
    lds_load16(smem + 4096 + w * 1024, as + 4096 + w * 1024 + lane * 16);
    lds_load16(smem + 8192 + w * 1024, bs + w * 1024 + lane * 16);
    lds_load16(smem + 12288 + w * 1024, bs + 4096 + w * 1024 + lane * 16);
    __syncthreads();

    bf16x8 af[4], bfr[4];
#pragma unroll
    for (int i = 0; i < 4; ++i)
      af[i] = *(const bf16x8*)&lA[(wm * 64 + i * 16 + fr) * 32 + fq * 8];
#pragma unroll
    for (int j = 0; j < 4; ++j)
      bfr[j] = *(const bf16x8*)&lB[(wn * 64 + j * 16 + fr) * 32 + fq * 8];
#pragma unroll
    for (int i = 0; i < 4; ++i)
#pragma unroll
      for (int j = 0; j < 4; ++j)
        acc[i][j] = __builtin_amdgcn_mfma_f32_16x16x32_bf16(af[i], bfr[j], acc[i][j], 0, 0, 0);
    __syncthreads();
  }

  // epilogue: bias + relu + scatter to out rows, coalesced via LDS round-trip.
  float bias[4];
#pragma unroll
  for (int j = 0; j < 4; ++j)
    bias[j] = b2[e * HID + nx * 128 + wn * 64 + j * 16 + fr];

  float* lsf = (float*)smem;                    // per-wave 1024 floats @ w*1024
  int lr = lane >> 2;
#pragma unroll
  for (int i = 0; i < 4; ++i) {
    __syncthreads();
#pragma unroll
    for (int j = 0; j < 4; ++j)
#pragma unroll
      for (int rg = 0; rg < 4; ++rg) {
        float v = acc[i][j][rg] + bias[j];
        lsf[w * 1024 + (fq * 4 + rg) * 64 + j * 16 + fr] = v > 0.f ? v : 0.f;
      }
    __syncthreads();
    int R = wm * 64 + i * 16 + lr;
    if (R < ce - rs) {
      float* orow = out + (size_t)toks[R] * HID + nx * 128 + wn * 64;
#pragma unroll
      for (int s = 0; s < 4; ++s) {
        int ch = (lane & 3) + s * 4;
        *(float4*)(orow + ch * 4) = *(const float4*)&lsf[w * 1024 + lr * 64 + ch * 4];
      }
    }
  }
}

// ---------------- workspace layout (bytes) ----------------
// cnt     @ 0          (8*64 = 512, padded 1 line/expert)
// ntiles  @ 1024       (4)
// desc    @ 1280       (1088)
// idx     @ 4096       (524288)
// W1p     @ 528384     (25165824)
// W2p     @ 25694208   (16777216)
// hp      @ 42471424   (35651584)
// Ap      @ 78123008   (136*48*8192 = 53477376) -> end 131600384 (~131.6 MB)

extern "C" void kernel_launch(void* const* d_in, const int* in_sizes, int n_in,
                              void* d_out, int out_size, void* d_ws, size_t ws_size,
                              hipStream_t stream) {
  const float* x   = (const float*)d_in[0];
  const int*   ops = (const int*)d_in[1];
  const float* emb = (const float*)d_in[2];
  const float* W1  = (const float*)d_in[3];
  const float* b1  = (const float*)d_in[4];
  const float* W2  = (const float*)d_in[5];
  const float* b2  = (const float*)d_in[6];
  float* out = (float*)d_out;

  char* ws = (char*)d_ws;
  int* cnt  = (int*)(ws + 0);
  int* ntp  = (int*)(ws + 1024);
  int* desc = (int*)(ws + 1280);
  int* idx  = (int*)(ws + 4096);
  short* W1p = (short*)(ws + 528384);
  short* W2p = (short*)(ws + 25694208);
  unsigned short* hp = (unsigned short*)(ws + 42471424);
  short* Ap = (short*)(ws + 78123008);

  hipMemsetAsync(cnt, 0, 512, stream);
  bucket_w1_k<<<64 + 3072, 256, 0, stream>>>(ops, cnt, idx, W1, W1p);
  schedule_k<<<1, 256, 0, stream>>>(cnt, desc, ntp, idx);
  prep_a_k<<<12 * MAXT, 256, 0, stream>>>(x, emb, idx, desc, ntp, Ap);
  gemm1_w2_k<<<8 * MAXT + 2048, 256, 0, stream>>>(Ap, b1, W1p, hp, desc, ntp, W2, W2p);
  gemm2_k<<<8 * MAXT, 256, 0, stream>>>(hp, b2, W2p, out, idx, cnt, desc, ntp);
}